// Round 8
// baseline (249.527 us; speedup 1.0000x reference)
//
#include <hip/hip_runtime.h>

#define HID 32
#define CAP 32   // bucket capacity; indegree ~ Poisson(4), P(deg>32) ~ 1e-19

// ---- build dst-bucketed edge permutation (one pass, int atomics only) ----
// node v owns slots [v*CAP, v*CAP+deg[v]); perm_src zero-initialized by host-side
// memset, so slots >= deg hold node 0 (always safe to gather, gated at compute).
__global__ __launch_bounds__(256) void build_kernel(
    const int* __restrict__ src, const int* __restrict__ dst,
    const float* __restrict__ ea,
    int* __restrict__ deg, int* __restrict__ perm_src, float4* __restrict__ perm_ea,
    int E)
{
    int e = blockIdx.x * blockDim.x + threadIdx.x;
    if (e >= E) return;
    int d = dst[e];
    int pos = atomicAdd(deg + d, 1) & (CAP - 1);    // mask: memory-safe even on impossible overflow
    size_t slot = (size_t)d * CAP + pos;
    perm_src[slot] = src[e];
    perm_ea[slot]  = *(const float4*)(ea + (size_t)e * 4);
}

// ---- 4-input-channel quad of the fused edge-MLP + msg dot ----
// t_i = relu(ea . w[:,i,o] + b[i,o]);  acc += x_i * t_i   for 4 consecutive i
__device__ __forceinline__ float edge_quad(const float4 av, const float4 xv,
                                           const float4 WA, const float4 WB,
                                           const float4 WC, const float4 WD,
                                           const float4 BR, float acc)
{
    float t;
    t = fmaf(av.x, WA.x, BR.x); t = fmaf(av.y, WB.x, t); t = fmaf(av.z, WC.x, t); t = fmaf(av.w, WD.x, t);
    acc = fmaf(xv.x, fmaxf(t, 0.f), acc);
    t = fmaf(av.x, WA.y, BR.y); t = fmaf(av.y, WB.y, t); t = fmaf(av.z, WC.y, t); t = fmaf(av.w, WD.y, t);
    acc = fmaf(xv.y, fmaxf(t, 0.f), acc);
    t = fmaf(av.x, WA.z, BR.z); t = fmaf(av.y, WB.z, t); t = fmaf(av.z, WC.z, t); t = fmaf(av.w, WD.z, t);
    acc = fmaf(xv.z, fmaxf(t, 0.f), acc);
    t = fmaf(av.x, WA.w, BR.w); t = fmaf(av.y, WB.w, t); t = fmaf(av.z, WC.w, t); t = fmaf(av.w, WD.w, t);
    acc = fmaf(xv.w, fmaxf(t, 0.f), acc);
    return acc;
}

// ---- layer-1 pull (IN=8): 64-lane wave per node; o = lane&31, half = lane>>5
// owns input channels half*4..half*4+3. Weight state = 6 float4 = 24 regs ->
// pure-register, high occupancy (6 waves/EU requested).
__global__ __launch_bounds__(256, 6) void pull8_kernel(
    const float* __restrict__ x,                    // [N, 8]
    const int* __restrict__ deg,
    const int* __restrict__ perm_src, const float4* __restrict__ perm_ea,
    const float* __restrict__ w_mlp,                // [4, 8*HID]
    const float* __restrict__ b_mlp,                // [8*HID]
    const float* __restrict__ root,                 // [8, HID]
    const float* __restrict__ bias,                 // [HID]
    float* __restrict__ h_out,                      // [N, HID]
    int N)
{
    constexpr int IN = 8, NPG = 4;
    const int lane = threadIdx.x & 63;
    const int o = lane & 31, half = lane >> 5;
    const int wave = (blockIdx.x * blockDim.x + threadIdx.x) >> 6;
    const int v0 = wave * NPG;
    if (v0 >= N) return;

    const int cb = half * 4 * HID + o;              // i = half*4 + {0..3}; coalesced per load
    const float4 WA = make_float4(w_mlp[cb],       w_mlp[cb+32],       w_mlp[cb+64],       w_mlp[cb+96]);
    const float4 WB = make_float4(w_mlp[256+cb],   w_mlp[256+cb+32],   w_mlp[256+cb+64],   w_mlp[256+cb+96]);
    const float4 WC = make_float4(w_mlp[512+cb],   w_mlp[512+cb+32],   w_mlp[512+cb+64],   w_mlp[512+cb+96]);
    const float4 WD = make_float4(w_mlp[768+cb],   w_mlp[768+cb+32],   w_mlp[768+cb+64],   w_mlp[768+cb+96]);
    const float4 BR = make_float4(b_mlp[cb],       b_mlp[cb+32],       b_mlp[cb+64],       b_mlp[cb+96]);
    const float4 RO = make_float4(root[cb],        root[cb+32],        root[cb+64],        root[cb+96]);
    const float bo = bias[o];

    for (int nv = 0; nv < NPG; ++nv) {
        const int v = v0 + nv;
        if (v >= N) break;
        const int dt = deg[v];
        const int dg = min(dt, CAP);
        const int* ps = perm_src + (size_t)v * CAP;
        const float4* pe = perm_ea + (size_t)v * CAP;

        float acc = 0.f;
        for (int k0 = 0; k0 < dg; k0 += 4) {
            int4 s4 = *(const int4*)(ps + k0);      // stale slots = 0 (zero-init): safe
            const int ss[4] = { s4.x, s4.y, s4.z, s4.w };
            float4 aa[4];
            #pragma unroll
            for (int j = 0; j < 4; ++j) aa[j] = pe[k0 + j];
            float4 xg[4];
            #pragma unroll
            for (int j = 0; j < 4; ++j)
                xg[j] = *(const float4*)(x + (size_t)ss[j] * IN + half * 4);
            #pragma unroll
            for (int j = 0; j < 4; ++j)
                if (k0 + j < dg)                    // wave-uniform gate
                    acc = edge_quad(aa[j], xg[j], WA, WB, WC, WD, BR, acc);
        }
        const float4 xr = *(const float4*)(x + (size_t)v * IN + half * 4);
        float rpart = fmaf(xr.x, RO.x, fmaf(xr.y, RO.y, fmaf(xr.z, RO.z, xr.w * RO.w)));
        float part = acc / fmaxf((float)dt, 1.f) + rpart;
        part += __shfl_down(part, 32);              // combine halves
        if (lane < 32)
            h_out[(size_t)v * HID + o] = fmaxf(part + bo, 0.f);
    }
}

// ---- layers 2/3 pull (IN=32): 64-lane wave per node; o = lane&31, half = lane>>5
// owns 16 input channels. Weight columns (WA..WD,BR = 20 f4 = 80 VGPR) are
// PINNED via empty asm "+v": R4/R6 showed the scheduler rematerializes
// loop-invariant weight loads to chase 128-VGPR occupancy (VGPR_Count=120 in
// both), re-inserting ~20 loads per batch. asm-defined values cannot be
// remat'd -> they stay resident; waves_per_eu(2,2) provides the 256-reg budget.
// Node-granular pipeline: next node's meta + first-2 gathers prefetched; rows
// 2-3 + own-row issued at compute start (covered by ~384cy of batch-0/1 FMAs).
template<bool HEAD>
__global__ __launch_bounds__(256) __attribute__((amdgpu_waves_per_eu(2, 2)))
void pull32_kernel(
    const float* __restrict__ h_in,                 // [N, 32]
    const int* __restrict__ deg,
    const int* __restrict__ perm_src, const float4* __restrict__ perm_ea,
    const float* __restrict__ w_mlp,                // [4, 32*HID]
    const float* __restrict__ b_mlp,                // [32*HID]
    const float* __restrict__ root,                 // [32, HID]
    const float* __restrict__ bias,                 // [HID]
    const float* __restrict__ hw1, const float* __restrict__ hb1,  // head
    const float* __restrict__ hw2, const float* __restrict__ hb2,  // head
    float* __restrict__ h_out,                      // [N, HID] or [N] if HEAD
    int N)
{
    constexpr int IN = 32, NPW = 8;
    const int lane = threadIdx.x & 63;
    const int o = lane & 31, half = lane >> 5;
    const int wave = (blockIdx.x * blockDim.x + threadIdx.x) >> 6;
    const int v0 = wave * NPW;
    if (v0 >= N) return;
    const int vEnd = min(v0 + NPW, N);
    const int hoff = half << 4;

    // weight columns: 20 float4, loaded once, PINNED (cannot be remat'd)
    float4 WA[4], WB[4], WC[4], WD[4], BR[4];
    #pragma unroll
    for (int k = 0; k < 4; ++k) {
        const int ib = (hoff + (k << 2)) * HID + o;
        WA[k] = make_float4(w_mlp[ib],      w_mlp[ib+32],      w_mlp[ib+64],      w_mlp[ib+96]);
        WB[k] = make_float4(w_mlp[1024+ib], w_mlp[1024+ib+32], w_mlp[1024+ib+64], w_mlp[1024+ib+96]);
        WC[k] = make_float4(w_mlp[2048+ib], w_mlp[2048+ib+32], w_mlp[2048+ib+64], w_mlp[2048+ib+96]);
        WD[k] = make_float4(w_mlp[3072+ib], w_mlp[3072+ib+32], w_mlp[3072+ib+64], w_mlp[3072+ib+96]);
        BR[k] = make_float4(b_mlp[ib],      b_mlp[ib+32],      b_mlp[ib+64],      b_mlp[ib+96]);
    }
    #pragma unroll
    for (int k = 0; k < 4; ++k) {
        asm volatile("" : "+v"(WA[k].x), "+v"(WA[k].y), "+v"(WA[k].z), "+v"(WA[k].w));
        asm volatile("" : "+v"(WB[k].x), "+v"(WB[k].y), "+v"(WB[k].z), "+v"(WB[k].w));
        asm volatile("" : "+v"(WC[k].x), "+v"(WC[k].y), "+v"(WC[k].z), "+v"(WC[k].w));
        asm volatile("" : "+v"(WD[k].x), "+v"(WD[k].y), "+v"(WD[k].z), "+v"(WD[k].w));
        asm volatile("" : "+v"(BR[k].x), "+v"(BR[k].y), "+v"(BR[k].z), "+v"(BR[k].w));
    }
    const float bo = bias[o];

    // ---- prologue: node v0's meta + first-2 neighbor rows ----
    int dgC = deg[v0];
    int s2C, s3C;
    float4 aaC[4], xg0[4], xg1[4];
    {
        int4 s4 = *(const int4*)(perm_src + (size_t)v0 * CAP);   // zero-init: valid ids
        s2C = s4.z; s3C = s4.w;
        #pragma unroll
        for (int j = 0; j < 4; ++j) aaC[j] = perm_ea[(size_t)v0 * CAP + j];
        const float* p0 = h_in + (size_t)s4.x * IN + hoff;
        const float* p1 = h_in + (size_t)s4.y * IN + hoff;
        #pragma unroll
        for (int q = 0; q < 4; ++q) { xg0[q] = *(const float4*)(p0 + 4*q); xg1[q] = *(const float4*)(p1 + 4*q); }
    }

    for (int nv = 0; nv < NPW; ++nv) {
        const int v = v0 + nv;
        if (v >= vEnd) break;
        const int dgc = min(dgC, CAP);

        // 1) rows 2-3 of current node (covered by batch-0/1 compute below)
        float4 xg2[4], xg3[4];
        {
            const float* p2 = h_in + (size_t)s2C * IN + hoff;
            const float* p3 = h_in + (size_t)s3C * IN + hoff;
            #pragma unroll
            for (int q = 0; q < 4; ++q) { xg2[q] = *(const float4*)(p2 + 4*q); xg3[q] = *(const float4*)(p3 + 4*q); }
        }
        // 2) own row
        float4 rC[4];
        {
            const float* rp = h_in + (size_t)v * IN + hoff;
            #pragma unroll
            for (int q = 0; q < 4; ++q) rC[q] = *(const float4*)(rp + 4*q);
        }
        // 3) prefetch next node: meta + first-2 rows
        const int vN = v + 1;
        const bool haveN = (vN < vEnd);
        int dgN = 0, s2N = 0, s3N = 0;
        float4 aaN[4], xn0[4], xn1[4];
        if (haveN) {
            dgN = deg[vN];
            int4 s4 = *(const int4*)(perm_src + (size_t)vN * CAP);
            s2N = s4.z; s3N = s4.w;
            #pragma unroll
            for (int j = 0; j < 4; ++j) aaN[j] = perm_ea[(size_t)vN * CAP + j];
            const float* p0 = h_in + (size_t)s4.x * IN + hoff;
            const float* p1 = h_in + (size_t)s4.y * IN + hoff;
            #pragma unroll
            for (int q = 0; q < 4; ++q) { xn0[q] = *(const float4*)(p0 + 4*q); xn1[q] = *(const float4*)(p1 + 4*q); }
        }

        // 4) compute batch 0 (neighbors 0-3), wave-uniform gates
        float acc = 0.f;
        #pragma unroll
        for (int j = 0; j < 4; ++j) {
            if (j < dgc) {
                #pragma unroll
                for (int k = 0; k < 4; ++k) {
                    const float4 xv = (j == 0) ? xg0[k] : (j == 1) ? xg1[k] : (j == 2) ? xg2[k] : xg3[k];
                    acc = edge_quad(aaC[j], xv, WA[k], WB[k], WC[k], WD[k], BR[k], acc);
                }
            }
        }

        // 5) tail batches (deg > 4, ~37% of nodes; hidden by co-resident wave)
        for (int k0 = 4; k0 < dgc; k0 += 4) {
            const int* ps = perm_src + (size_t)v * CAP + k0;
            const float4* pe = perm_ea + (size_t)v * CAP + k0;
            int4 s4 = *(const int4*)(ps);
            const int st[4] = { s4.x, s4.y, s4.z, s4.w };
            float4 at[4], xt[4][4];
            #pragma unroll
            for (int j = 0; j < 4; ++j) at[j] = pe[j];
            #pragma unroll
            for (int j = 0; j < 4; ++j) {
                const float* xp = h_in + (size_t)st[j] * IN + hoff;
                #pragma unroll
                for (int q = 0; q < 4; ++q) xt[j][q] = *(const float4*)(xp + 4*q);
            }
            #pragma unroll
            for (int j = 0; j < 4; ++j) {
                if (k0 + j < dgc) {
                    #pragma unroll
                    for (int k = 0; k < 4; ++k)
                        acc = edge_quad(at[j], xt[j][k], WA[k], WB[k], WC[k], WD[k], BR[k], acc);
                }
            }
        }

        // 6) finalize: root partial (RO unpinned: loaded per node, L1-resident)
        float rpart = 0.f;
        #pragma unroll
        for (int k = 0; k < 4; ++k) {
            const int ib = (hoff + (k << 2)) * HID + o;
            const float4 RO = make_float4(root[ib], root[ib+32], root[ib+64], root[ib+96]);
            rpart = fmaf(rC[k].x, RO.x, rpart);
            rpart = fmaf(rC[k].y, RO.y, rpart);
            rpart = fmaf(rC[k].z, RO.z, rpart);
            rpart = fmaf(rC[k].w, RO.w, rpart);
        }
        float part = acc / fmaxf((float)dgC, 1.f) + rpart;
        part += __shfl_down(part, 32);              // combine i-halves
        if (lane < 32) {
            float h = fmaxf(part + bo, 0.f);
            if (!HEAD) {
                h_out[(size_t)v * HID + o] = h;
            } else {
                float tt = hb1[o];
                #pragma unroll
                for (int i = 0; i < HID; ++i)
                    tt = fmaf(__shfl(h, i, 32), hw1[i * HID + o], tt);
                tt = fmaxf(tt, 0.f) * hw2[o];
                #pragma unroll
                for (int dd = 16; dd > 0; dd >>= 1)
                    tt += __shfl_down(tt, dd, 32);
                if (o == 0) h_out[v] = tt + hb2[0];
            }
        }

        // 7) rotate next -> current
        dgC = dgN; s2C = s2N; s3C = s3N;
        #pragma unroll
        for (int j = 0; j < 4; ++j) aaC[j] = aaN[j];
        #pragma unroll
        for (int q = 0; q < 4; ++q) { xg0[q] = xn0[q]; xg1[q] = xn1[q]; }
    }
}

extern "C" void kernel_launch(void* const* d_in, const int* in_sizes, int n_in,
                              void* d_out, int out_size, void* d_ws, size_t ws_size,
                              hipStream_t stream)
{
    const float* x      = (const float*)d_in[0];
    const int*   ei     = (const int*)d_in[1];     // [2, E] int32
    const float* ea     = (const float*)d_in[2];
    const float* w_mlp1 = (const float*)d_in[3];
    const float* b_mlp1 = (const float*)d_in[4];
    const float* root1  = (const float*)d_in[5];
    const float* bias1  = (const float*)d_in[6];
    const float* w_mlp2 = (const float*)d_in[7];
    const float* b_mlp2 = (const float*)d_in[8];
    const float* root2  = (const float*)d_in[9];
    const float* bias2  = (const float*)d_in[10];
    const float* w_mlp3 = (const float*)d_in[11];
    const float* b_mlp3 = (const float*)d_in[12];
    const float* root3  = (const float*)d_in[13];
    const float* bias3  = (const float*)d_in[14];
    const float* w_out1 = (const float*)d_in[15];
    const float* b_out1 = (const float*)d_in[16];
    const float* w_out2 = (const float*)d_in[17];
    const float* b_out2 = (const float*)d_in[18];

    const int NODE_IN = 8;
    const int N = in_sizes[0] / NODE_IN;            // 25000
    const int E = in_sizes[2] / 4;                  // 100000
    const int* src = ei;
    const int* dst = ei + E;

    // workspace carve-up (deg and perm_src adjacent: one memset zeroes both)
    char* ws = (char*)d_ws;
    size_t off = 0;
    auto carve = [&](size_t bytes) {
        char* p = ws + off;
        off += (bytes + 255) & ~(size_t)255;
        return p;
    };
    int*    deg      = (int*)carve((size_t)N * 4);                  // 100 KB
    int*    perm_src = (int*)carve((size_t)N * CAP * 4);            // 3.2 MB
    float4* perm_ea  = (float4*)carve((size_t)N * CAP * 16);        // 12.8 MB
    float*  h1       = (float*)carve((size_t)N * HID * 4);          // 3.2 MB
    float*  h2       = (float*)carve((size_t)N * HID * 4);          // 3.2 MB
    float*  outp     = (float*)d_out;
    size_t zero_bytes = (size_t)((char*)perm_src - (char*)deg) + (size_t)N * CAP * 4;

    const int TB = 256;
    const int buildBlocks = (E + TB - 1) / TB;                      // 391
    const int p8Blocks  = (N + 4 * 4 - 1) / (4 * 4);                // NPG=4, 4 waves/block -> 1563
    const int p32Blocks = (N + 8 * 4 - 1) / (8 * 4);                // NPW=8, 4 waves/block -> 782

    // 1) zero deg + perm_src (3.3 MB; stale perm_src slots must be node 0)
    hipMemsetAsync(deg, 0, zero_bytes, stream);

    // 2) build dst-bucketed edge permutation (reused by all 3 layers)
    build_kernel<<<buildBlocks, TB, 0, stream>>>(src, dst, ea, deg, perm_src, perm_ea, E);

    // 3) conv1: pull + fused node update  (x -> h1)
    pull8_kernel<<<p8Blocks, TB, 0, stream>>>(x, deg, perm_src, perm_ea,
                                              w_mlp1, b_mlp1, root1, bias1, h1, N);

    // 4) conv2: pull + fused node update  (h1 -> h2)
    pull32_kernel<false><<<p32Blocks, TB, 0, stream>>>(h1, deg, perm_src, perm_ea,
                                                       w_mlp2, b_mlp2, root2, bias2,
                                                       nullptr, nullptr, nullptr, nullptr, h2, N);

    // 5) conv3 + output head fused  (h2 -> out)
    pull32_kernel<true><<<p32Blocks, TB, 0, stream>>>(h2, deg, perm_src, perm_ea,
                                                      w_mlp3, b_mlp3, root3, bias3,
                                                      w_out1, b_out1, w_out2, b_out2, outp, N);
}

// Round 9
// 222.687 us; speedup vs baseline: 1.1205x; 1.1205x over previous
//
#include <hip/hip_runtime.h>

#define HID 32
#define CAP 32   // slot capacity per node; indegree ~ Poisson(4), P(deg>32) ~ 1e-19

// ---- build: in-degree + per-edge slot assignment (int atomics only) ----
// eslot[e] = dst[e]*CAP + arrival_pos. Each edge gets a unique slot; phase A
// stores its message there, phase B sums slots [v*CAP, v*CAP+deg[v]).
__global__ __launch_bounds__(256) void build_kernel(
    const int* __restrict__ dst,
    int* __restrict__ deg, int* __restrict__ eslot, int E)
{
    int e = blockIdx.x * blockDim.x + threadIdx.x;
    if (e >= E) return;
    int d = dst[e];
    int pos = atomicAdd(deg + d, 1) & (CAP - 1);    // mask: memory-safe on impossible overflow
    eslot[e] = d * CAP + pos;
}

// ---- phase A, layer 1 (IN=8): 32-lane group per edge, grid-stride, 1-ahead
// prefetch. lane = output channel; weight column 40 regs. NO atomics: message
// stored to the edge's private slot (coalesced 128B per group).
__global__ __launch_bounds__(256) void msg8_kernel(
    const float* __restrict__ x,                    // [N, 8]
    const int* __restrict__ src, const int* __restrict__ eslot,
    const float* __restrict__ ea,                   // [E, 4]
    const float* __restrict__ w_mlp,                // [4, 8*HID]
    const float* __restrict__ b_mlp,                // [8*HID]
    float* __restrict__ msg,                        // [N*CAP, HID]
    int E)
{
    constexpr int IN = 8;
    const int o    = threadIdx.x & 31;
    const int grp  = (blockIdx.x * blockDim.x + threadIdx.x) >> 5;
    const int ngrp = (gridDim.x * blockDim.x) >> 5;

    float w0[IN], w1[IN], w2[IN], w3[IN], br[IN];
    #pragma unroll
    for (int i = 0; i < IN; ++i) {
        int c = i * HID + o;                        // coalesced across lanes
        w0[i] = w_mlp[c];
        w1[i] = w_mlp[IN * HID + c];
        w2[i] = w_mlp[2 * IN * HID + c];
        w3[i] = w_mlp[3 * IN * HID + c];
        br[i] = b_mlp[c];
    }

    int e = grp;
    if (e >= E) return;
    int sl = eslot[e];
    float4 a = *(const float4*)(ea + (size_t)e * 4);
    float4 xv0 = *(const float4*)(x + (size_t)src[e] * IN);
    float4 xv1 = *(const float4*)(x + (size_t)src[e] * IN + 4);

    while (true) {
        const int e2 = e + ngrp;
        const bool more = (e2 < E);
        int sl2 = 0;
        float4 a2 = make_float4(0.f, 0.f, 0.f, 0.f), xn0 = a2, xn1 = a2;
        if (more) {
            sl2 = eslot[e2];
            a2 = *(const float4*)(ea + (size_t)e2 * 4);
            const int s2 = src[e2];
            xn0 = *(const float4*)(x + (size_t)s2 * IN);
            xn1 = *(const float4*)(x + (size_t)s2 * IN + 4);
        }

        float acc = 0.f;
        const float xs[8] = { xv0.x, xv0.y, xv0.z, xv0.w, xv1.x, xv1.y, xv1.z, xv1.w };
        #pragma unroll
        for (int i = 0; i < IN; ++i) {
            float t = fmaf(a.x, w0[i], br[i]);
            t = fmaf(a.y, w1[i], t);
            t = fmaf(a.z, w2[i], t);
            t = fmaf(a.w, w3[i], t);
            acc = fmaf(xs[i], fmaxf(t, 0.f), acc);
        }
        msg[(size_t)sl * HID + o] = acc;            // plain store, no RMW

        if (!more) break;
        e = e2; sl = sl2; a = a2; xv0 = xn0; xv1 = xn1;
    }
}

// ---- phase A, layers 2/3 (IN=32): 64-lane wave per edge; o = lane&31,
// half = lane>>5 owns 16 input channels (weight column 80 regs). Grid-stride,
// 1-ahead prefetch (R1's proven 112-VGPR structure). Halves combined with one
// shfl; lanes 0-31 store the message to the edge's slot. NO atomics.
__global__ __launch_bounds__(256) void msg32_kernel(
    const float* __restrict__ h_in,                 // [N, 32]
    const int* __restrict__ src, const int* __restrict__ eslot,
    const float* __restrict__ ea,                   // [E, 4]
    const float* __restrict__ w_mlp,                // [4, 32*HID]
    const float* __restrict__ b_mlp,                // [32*HID]
    float* __restrict__ msg,                        // [N*CAP, HID]
    int E)
{
    constexpr int IN = 32, IH = 16;
    const int lane = threadIdx.x & 63;
    const int o = lane & 31, half = lane >> 5;
    const int wave  = (blockIdx.x * blockDim.x + threadIdx.x) >> 6;
    const int nwave = (gridDim.x * blockDim.x) >> 6;
    const int hoff = half << 4;

    float w0[IH], w1[IH], w2[IH], w3[IH], br[IH];
    #pragma unroll
    for (int i = 0; i < IH; ++i) {
        int c = (hoff + i) * HID + o;
        w0[i] = w_mlp[c];
        w1[i] = w_mlp[IN * HID + c];
        w2[i] = w_mlp[2 * IN * HID + c];
        w3[i] = w_mlp[3 * IN * HID + c];
        br[i] = b_mlp[c];
    }

    int e = wave;
    if (e >= E) return;
    int sl = eslot[e];
    float4 a = *(const float4*)(ea + (size_t)e * 4);
    float4 xv[4];
    {
        const float* xp = h_in + (size_t)src[e] * IN + hoff;
        #pragma unroll
        for (int q = 0; q < 4; ++q) xv[q] = *(const float4*)(xp + 4 * q);
    }

    while (true) {
        const int e2 = e + nwave;
        const bool more = (e2 < E);
        int sl2 = 0;
        float4 a2 = make_float4(0.f, 0.f, 0.f, 0.f);
        float4 xn[4] = { a2, a2, a2, a2 };
        if (more) {
            sl2 = eslot[e2];
            a2 = *(const float4*)(ea + (size_t)e2 * 4);
            const float* xp = h_in + (size_t)src[e2] * IN + hoff;
            #pragma unroll
            for (int q = 0; q < 4; ++q) xn[q] = *(const float4*)(xp + 4 * q);
        }

        float acc = 0.f;
        #pragma unroll
        for (int q = 0; q < 4; ++q) {
            const float xs[4] = { xv[q].x, xv[q].y, xv[q].z, xv[q].w };
            #pragma unroll
            for (int j = 0; j < 4; ++j) {
                const int i = q * 4 + j;
                float t = fmaf(a.x, w0[i], br[i]);
                t = fmaf(a.y, w1[i], t);
                t = fmaf(a.z, w2[i], t);
                t = fmaf(a.w, w3[i], t);
                acc = fmaf(xs[j], fmaxf(t, 0.f), acc);
            }
        }
        acc += __shfl_down(acc, 32);                // combine i-halves
        if (lane < 32) msg[(size_t)sl * HID + o] = acc;   // plain store

        if (!more) break;
        e = e2; sl = sl2; a = a2;
        #pragma unroll
        for (int q = 0; q < 4; ++q) xv[q] = xn[q];
    }
}

// ---- phase B: segmented reduce over a node's slots + fused node update ----
// 32-lane group per node; lane = output channel. Reads deg rows of 128B
// (contiguous), adds x@root + bias, relu. HEAD additionally applies the
// output MLP (h3 never materialized).
template<int IN, bool HEAD>
__global__ __launch_bounds__(256) void reduce_kernel(
    const float* __restrict__ x_in,                 // [N, IN]
    const int* __restrict__ deg,
    const float* __restrict__ msg,                  // [N*CAP, HID]
    const float* __restrict__ root,                 // [IN, HID]
    const float* __restrict__ bias,                 // [HID]
    const float* __restrict__ hw1, const float* __restrict__ hb1,  // head
    const float* __restrict__ hw2, const float* __restrict__ hb2,  // head
    float* __restrict__ out,                        // [N, HID] or [N] if HEAD
    int N)
{
    const int idx = blockIdx.x * blockDim.x + threadIdx.x;
    const int v = idx >> 5, o = idx & 31;
    if (v >= N) return;

    const int dt = deg[v];
    const int dg = min(dt, CAP);
    const float* mp = msg + (size_t)v * CAP * HID + o;
    float m = 0.f;
    for (int k = 0; k < dg; ++k)
        m += mp[k * HID];                           // lane o reads element o: coalesced 128B/k

    float r = bias[o];
    const float* xv = x_in + (size_t)v * IN;
    #pragma unroll
    for (int i = 0; i < IN; ++i)
        r = fmaf(xv[i], root[i * HID + o], r);

    float h = fmaxf(m / fmaxf((float)dt, 1.f) + r, 0.f);
    if (!HEAD) {
        out[(size_t)v * HID + o] = h;
    } else {
        float t = hb1[o];
        #pragma unroll
        for (int i = 0; i < HID; ++i)
            t = fmaf(__shfl(h, i, 32), hw1[i * HID + o], t);
        t = fmaxf(t, 0.f) * hw2[o];
        #pragma unroll
        for (int dd = 16; dd > 0; dd >>= 1)
            t += __shfl_down(t, dd, 32);
        if (o == 0) out[v] = t + hb2[0];
    }
}

extern "C" void kernel_launch(void* const* d_in, const int* in_sizes, int n_in,
                              void* d_out, int out_size, void* d_ws, size_t ws_size,
                              hipStream_t stream)
{
    const float* x      = (const float*)d_in[0];
    const int*   ei     = (const int*)d_in[1];     // [2, E] int32
    const float* ea     = (const float*)d_in[2];
    const float* w_mlp1 = (const float*)d_in[3];
    const float* b_mlp1 = (const float*)d_in[4];
    const float* root1  = (const float*)d_in[5];
    const float* bias1  = (const float*)d_in[6];
    const float* w_mlp2 = (const float*)d_in[7];
    const float* b_mlp2 = (const float*)d_in[8];
    const float* root2  = (const float*)d_in[9];
    const float* bias2  = (const float*)d_in[10];
    const float* w_mlp3 = (const float*)d_in[11];
    const float* b_mlp3 = (const float*)d_in[12];
    const float* root3  = (const float*)d_in[13];
    const float* bias3  = (const float*)d_in[14];
    const float* w_out1 = (const float*)d_in[15];
    const float* b_out1 = (const float*)d_in[16];
    const float* w_out2 = (const float*)d_in[17];
    const float* b_out2 = (const float*)d_in[18];

    const int NODE_IN = 8;
    const int N = in_sizes[0] / NODE_IN;            // 25000
    const int E = in_sizes[2] / 4;                  // 100000
    const int* src = ei;
    const int* dst = ei + E;

    // workspace carve-up
    char* ws = (char*)d_ws;
    size_t off = 0;
    auto carve = [&](size_t bytes) {
        char* p = ws + off;
        off += (bytes + 255) & ~(size_t)255;
        return p;
    };
    int*   deg   = (int*)carve((size_t)N * 4);                       // 100 KB
    int*   eslot = (int*)carve((size_t)E * 4);                       // 400 KB
    float* msg   = (float*)carve((size_t)N * CAP * HID * 4);         // 102.4 MB (only deg-slots touched)
    float* h1    = (float*)carve((size_t)N * HID * 4);               // 3.2 MB
    float* h2    = (float*)carve((size_t)N * HID * 4);               // 3.2 MB
    float* outp  = (float*)d_out;

    const int TB = 256;
    const int buildBlocks  = (E + TB - 1) / TB;                      // 391
    const int msgBlocks    = 2048;                                   // 8192 waves / 16384 groups, grid-stride
    const int reduceBlocks = (N * HID + TB - 1) / TB;                // 3125

    // 1) zero deg only (100 KB; msg needs no zeroing - slots >= deg never read)
    hipMemsetAsync(deg, 0, (size_t)N * 4, stream);

    // 2) build slot assignment (reused by all 3 layers)
    build_kernel<<<buildBlocks, TB, 0, stream>>>(dst, deg, eslot, E);

    // 3) conv1: edge messages -> slots, then segmented reduce + node update
    msg8_kernel<<<msgBlocks, TB, 0, stream>>>(x, src, eslot, ea, w_mlp1, b_mlp1, msg, E);
    reduce_kernel<8, false><<<reduceBlocks, TB, 0, stream>>>(x, deg, msg, root1, bias1,
                                                             nullptr, nullptr, nullptr, nullptr, h1, N);

    // 4) conv2
    msg32_kernel<<<msgBlocks, TB, 0, stream>>>(h1, src, eslot, ea, w_mlp2, b_mlp2, msg, E);
    reduce_kernel<32, false><<<reduceBlocks, TB, 0, stream>>>(h1, deg, msg, root2, bias2,
                                                              nullptr, nullptr, nullptr, nullptr, h2, N);

    // 5) conv3 + fused output head
    msg32_kernel<<<msgBlocks, TB, 0, stream>>>(h2, src, eslot, ea, w_mlp3, b_mlp3, msg, E);
    reduce_kernel<32, true><<<reduceBlocks, TB, 0, stream>>>(h2, deg, msg, root3, bias3,
                                                             w_out1, b_out1, w_out2, b_out2, outp, N);
}